// Round 10
// baseline (197.508 us; speedup 1.0000x reference)
//
#include <hip/hip_runtime.h>
#include <math.h>

#define INV2PI 0.15915494309189535f  // 1/(2*pi)

// Model (r6/r8/r9 differentials):
//  - per-SIMD issue work: trans 4096 x 8cyc + VALU ~16K cyc = ~48K cyc
//    => ~20.5 us issue floor.  r9 measured 45.5 us at 4 waves/SIMD,
//    VALUBusy 61%, Occupancy ~30% => latency-bound from too little TLP.
//  - VGPR=64 is exactly the 8-waves/SIMD boundary; grid only supplied 4.
// v9: 8 waves/SIMD.  Wave = (neuron-pair, b-octet): 8192 waves = 2048
// blocks.  Per-wave state halved: acc 32 VGPR, xv[4] batch, ~60 total;
// __launch_bounds__(256,8) pins the allocator to <=64 (est. 60, no spill).
// x read from L2 (256 KB resident), 2 neurons per x-load; W/Bp re-read
// x8 from L2/L3 (~134 MB) -- total L2 ~16 TB/s at 25 us, under ceiling.

// ---------------------------------------------------------------------------
// Kernel 1 (v9): sums.  lanes = d (2 d's per lane per chunk).
// Per chunk (128 d's): 4 float2 W/Bp loads, then 2 half-batches of
// {4 x-float2 loads, 16 elems = 32 trans}.
// Epilogue: per-wave XOR-swizzled LDS 8-row transpose reduce (4 passes) +
// shfl_xor(8,16,32), then rotation by t (exact identity):
//   sum cos(2pi a + t) = cos(t)*A_c - sin(t)*A_s
// ---------------------------------------------------------------------------
__global__ __launch_bounds__(256, 8) void k_sums(
    const float* __restrict__ x, const float* __restrict__ t,
    const float* __restrict__ W, const float* __restrict__ Bp,
    float2* __restrict__ S2)
{
    __shared__ float sl_all[4][512];   // 8 KB, epilogue only

    const int tid  = threadIdx.x;
    const int lane = tid & 63;
    const int w    = tid >> 6;                 // wave in block 0..3
    const int gw   = blockIdx.x * 4 + w;       // 0..8191
    const int n2   = gw >> 3;                  // neuron pair 0..1023
    const int be   = gw & 7;                   // b-octet (8 b's)
    const int n0   = n2 * 2, n1 = n0 + 1;

    float aC0[8], aS0[8], aC1[8], aS1[8];
    #pragma unroll
    for (int j = 0; j < 8; ++j) { aC0[j]=0.f; aS0[j]=0.f; aC1[j]=0.f; aS1[j]=0.f; }

    const float* xb = x + (size_t)(be * 8) * 1024 + 2 * lane;

    for (int c = 0; c < 8; ++c) {
        const int dof = c * 128;

        // per-chunk wavelength/phase params for both neurons (L2/L3-resident)
        const float2 w0 = *reinterpret_cast<const float2*>(W  + (size_t)n0 * 1024 + dof + 2 * lane);
        const float2 w1 = *reinterpret_cast<const float2*>(W  + (size_t)n1 * 1024 + dof + 2 * lane);
        const float2 p0 = *reinterpret_cast<const float2*>(Bp + (size_t)n0 * 1024 + dof + 2 * lane);
        const float2 p1 = *reinterpret_cast<const float2*>(Bp + (size_t)n1 * 1024 + dof + 2 * lane);
        const float iw0x = INV2PI / (1.f + fabsf(w0.x));
        const float iw0y = INV2PI / (1.f + fabsf(w0.y));
        const float iw1x = INV2PI / (1.f + fabsf(w1.x));
        const float iw1y = INV2PI / (1.f + fabsf(w1.y));
        const float bp0x = p0.x * INV2PI;
        const float bp0y = p0.y * INV2PI;
        const float bp1x = p1.x * INV2PI;
        const float bp1y = p1.y * INV2PI;

        // two half-batches of 4 b's: 4 independent L2 loads, then compute
        #pragma unroll
        for (int h = 0; h < 2; ++h) {
            float2 xv[4];
            #pragma unroll
            for (int j = 0; j < 4; ++j)
                xv[j] = *reinterpret_cast<const float2*>(xb + (size_t)(h * 4 + j) * 1024 + dof);

            #pragma unroll
            for (int j = 0; j < 4; ++j) {
                const int jj = h * 4 + j;
                float r;
                r = __builtin_amdgcn_fractf(fmaf(xv[j].x, iw0x, bp0x));
                aC0[jj] += __builtin_amdgcn_cosf(r);
                aS0[jj] += __builtin_amdgcn_sinf(r);
                r = __builtin_amdgcn_fractf(fmaf(xv[j].y, iw0y, bp0y));
                aC0[jj] += __builtin_amdgcn_cosf(r);
                aS0[jj] += __builtin_amdgcn_sinf(r);
                r = __builtin_amdgcn_fractf(fmaf(xv[j].x, iw1x, bp1x));
                aC1[jj] += __builtin_amdgcn_cosf(r);
                aS1[jj] += __builtin_amdgcn_sinf(r);
                r = __builtin_amdgcn_fractf(fmaf(xv[j].y, iw1y, bp1y));
                aC1[jj] += __builtin_amdgcn_cosf(r);
                aS1[jj] += __builtin_amdgcn_sinf(r);
            }
        }
    }

    // ---- epilogue: per-wave reduce of 4 acc sets across 64 lanes ----------
    float* sl = sl_all[w];                 // private per-wave slice, no sync
    const int g  = lane >> 3;              // 0..7
    const int bb = lane & 7;

    float sums[4];
    #pragma unroll
    for (int a = 0; a < 4; ++a) {
        const float* arr = (a == 0) ? aC0 : (a == 1) ? aS0 : (a == 2) ? aC1 : aS1;
        #pragma unroll
        for (int j = 0; j < 8; ++j) sl[j * 64 + (lane ^ j)] = arr[j];
        float s = 0.f;
        #pragma unroll
        for (int k = 0; k < 8; ++k) s += sl[bb * 64 + ((g * 8 + k) ^ bb)];
        s += __shfl_xor(s, 8);
        s += __shfl_xor(s, 16);
        s += __shfl_xor(s, 32);
        sums[a] = s;
    }

    if (lane < 8) {
        const int b  = be * 8 + lane;
        const float tv = t[b];
        const float ct = cosf(tv), st = sinf(tv);
        S2[n0 * 64 + b] = make_float2(ct * sums[0] - st * sums[1],
                                      st * sums[0] + ct * sums[1]);
        S2[n1 * 64 + b] = make_float2(ct * sums[2] - st * sums[3],
                                      st * sums[2] + ct * sums[3]);
    }
}

// ---------------------------------------------------------------------------
// Kernel 2: split-K GEMM (unchanged).
// out^T[d][b] = sum_n Pr[d][n]*c[n][b] + Pi[d][n]*s[n][b]
// grid = (128 d-tiles of 8, 8 k-chunks of 256).  Wave: 2 d-rows, lanes = b.
// ---------------------------------------------------------------------------
__global__ __launch_bounds__(256) void k_gemm(
    const float2* __restrict__ S2, const float* __restrict__ Pr,
    const float* __restrict__ Pi, float* __restrict__ partial)
{
    const int lane = threadIdx.x & 63;
    const int wid  = __builtin_amdgcn_readfirstlane(threadIdx.x >> 6);
    const int d0   = blockIdx.x * 8 + wid * 2;
    const int k0   = blockIdx.y * 256;

    const float* pr = Pr + (size_t)d0 * 2048 + k0;
    const float* pi = Pi + (size_t)d0 * 2048 + k0;

    float a0 = 0.f, a1 = 0.f;

    for (int kk = 0; kk < 256; kk += 8) {
        float2 cs[8];
        #pragma unroll
        for (int i = 0; i < 8; ++i)
            cs[i] = S2[(size_t)(k0 + kk + i) * 64 + lane];
        #pragma unroll
        for (int i = 0; i < 8; ++i) {
            a0 += pr[kk + i]        * cs[i].x + pi[kk + i]        * cs[i].y;
            a1 += pr[2048 + kk + i] * cs[i].x + pi[2048 + kk + i] * cs[i].y;
        }
    }

    float* p = partial + ((size_t)blockIdx.y * 1024 + d0) * 64 + lane;
    p[0]  = a0;
    p[64] = a1;
}

// ---------------------------------------------------------------------------
// Kernel 3: reduce 8 split-K partials + SiLU (unchanged).
// ---------------------------------------------------------------------------
__global__ __launch_bounds__(256, 4) void k_reduce_silu(
    const float* __restrict__ partial, float* __restrict__ out)
{
    const int lane = threadIdx.x & 63;
    const int gw   = blockIdx.x * 4 + (threadIdx.x >> 6);
    const int b    = gw >> 4;
    const int d    = ((gw & 15) << 6) + lane;

    float s = 0.f;
    #pragma unroll
    for (int ss = 0; ss < 8; ++ss)
        s += partial[((size_t)ss * 1024 + d) * 64 + b];

    float sig = 1.0f / (1.0f + __expf(-s));
    out[(size_t)b * 1024 + d] = s * sig;
}

// ---------------------------------------------------------------------------
extern "C" void kernel_launch(void* const* d_in, const int* in_sizes, int n_in,
                              void* d_out, int out_size, void* d_ws, size_t ws_size,
                              hipStream_t stream)
{
    const float* x  = (const float*)d_in[0];   // (64,1024)
    const float* t  = (const float*)d_in[1];   // (64,)
    const float* W  = (const float*)d_in[2];   // (2048,1024)
    const float* Bp = (const float*)d_in[3];   // (2048,1024)
    const float* Pr = (const float*)d_in[4];   // (1024,2048)
    const float* Pi = (const float*)d_in[5];   // (1024,2048)
    // d_in[6], d_in[7]: sin/cos LUT — superseded by hw sin/cos

    float*  out     = (float*)d_out;                       // (64,1024) f32
    float2* S2      = (float2*)d_ws;                       // 1 MB
    float*  partial = (float*)((char*)d_ws + (1 << 20));   // 2 MB

    k_sums<<<2048, 256, 0, stream>>>(x, t, W, Bp, S2);
    k_gemm<<<dim3(128, 8), 256, 0, stream>>>(S2, Pr, Pi, partial);
    k_reduce_silu<<<256, 256, 0, stream>>>(partial, out);
}

// Round 11
// 157.397 us; speedup vs baseline: 1.2548x; 1.2548x over previous
//
#include <hip/hip_runtime.h>
#include <math.h>

#define INV2PI 0.15915494309189535f  // 1/(2*pi)

// Model (r6/r8/r9/r10 differentials):
//  - issue floor ~28 us/SIMD: 2048 wave-groups x (2 trans x ~8.5 cyc +
//    ~15 cyc VALU incl. addressing); r9 ran at 61% of it on 4 waves/SIMD.
//  - r10: __launch_bounds__(256,8) made the allocator pick VGPR=32 (NOT the
//    64 that 8 waves permit) -> acc spilled to scratch (WRITE 88 MB) -> 88 us.
//    Grid-side occupancy fix itself worked (73%).
//  - unclamped compiler picked exactly 64 VGPR in v8 -> trust it.
// v10 = r10 kernel with the clamp DROPPED (only change).  8192 waves =
// 8/SIMD supply; ~60 VGPR of true state fits the 64-VGPR boundary.

// ---------------------------------------------------------------------------
// Kernel 1 (v10): sums.  lanes = d (2 d's per lane per chunk).
// Wave = (neuron pair, b-octet): 8192 waves = 2048 blocks x 256 thr.
// Zero barriers; x/W/Bp read straight from L2 (x 256 KB resident; each x
// float2 feeds 2 neurons x 2 d = 4 elements -> x L2 traffic ~268 MB).
// Per chunk (128 d's): 4 float2 W/Bp loads, then 2 half-batches of
// {4 x-float2 loads, 16 elems = 32 trans}.
// Epilogue: per-wave XOR-swizzled LDS 8-row transpose reduce + shfl_xor,
// then rotation by t (exact identity):
//   sum cos(2pi a + t) = cos(t)*A_c - sin(t)*A_s
// ---------------------------------------------------------------------------
__global__ __launch_bounds__(256) void k_sums(
    const float* __restrict__ x, const float* __restrict__ t,
    const float* __restrict__ W, const float* __restrict__ Bp,
    float2* __restrict__ S2)
{
    __shared__ float sl_all[4][512];   // 8 KB, epilogue only

    const int tid  = threadIdx.x;
    const int lane = tid & 63;
    const int w    = tid >> 6;                 // wave in block 0..3
    const int gw   = blockIdx.x * 4 + w;       // 0..8191
    const int n2   = gw >> 3;                  // neuron pair 0..1023
    const int be   = gw & 7;                   // b-octet (8 b's)
    const int n0   = n2 * 2, n1 = n0 + 1;

    float aC0[8], aS0[8], aC1[8], aS1[8];
    #pragma unroll
    for (int j = 0; j < 8; ++j) { aC0[j]=0.f; aS0[j]=0.f; aC1[j]=0.f; aS1[j]=0.f; }

    const float* xb = x + (size_t)(be * 8) * 1024 + 2 * lane;

    for (int c = 0; c < 8; ++c) {
        const int dof = c * 128;

        // per-chunk wavelength/phase params for both neurons (L2/L3-resident)
        const float2 w0 = *reinterpret_cast<const float2*>(W  + (size_t)n0 * 1024 + dof + 2 * lane);
        const float2 w1 = *reinterpret_cast<const float2*>(W  + (size_t)n1 * 1024 + dof + 2 * lane);
        const float2 p0 = *reinterpret_cast<const float2*>(Bp + (size_t)n0 * 1024 + dof + 2 * lane);
        const float2 p1 = *reinterpret_cast<const float2*>(Bp + (size_t)n1 * 1024 + dof + 2 * lane);
        const float iw0x = INV2PI / (1.f + fabsf(w0.x));
        const float iw0y = INV2PI / (1.f + fabsf(w0.y));
        const float iw1x = INV2PI / (1.f + fabsf(w1.x));
        const float iw1y = INV2PI / (1.f + fabsf(w1.y));
        const float bp0x = p0.x * INV2PI;
        const float bp0y = p0.y * INV2PI;
        const float bp1x = p1.x * INV2PI;
        const float bp1y = p1.y * INV2PI;

        // two half-batches of 4 b's: 4 independent L2 loads, then compute
        #pragma unroll
        for (int h = 0; h < 2; ++h) {
            float2 xv[4];
            #pragma unroll
            for (int j = 0; j < 4; ++j)
                xv[j] = *reinterpret_cast<const float2*>(xb + (size_t)(h * 4 + j) * 1024 + dof);

            #pragma unroll
            for (int j = 0; j < 4; ++j) {
                const int jj = h * 4 + j;
                float r;
                r = __builtin_amdgcn_fractf(fmaf(xv[j].x, iw0x, bp0x));
                aC0[jj] += __builtin_amdgcn_cosf(r);
                aS0[jj] += __builtin_amdgcn_sinf(r);
                r = __builtin_amdgcn_fractf(fmaf(xv[j].y, iw0y, bp0y));
                aC0[jj] += __builtin_amdgcn_cosf(r);
                aS0[jj] += __builtin_amdgcn_sinf(r);
                r = __builtin_amdgcn_fractf(fmaf(xv[j].x, iw1x, bp1x));
                aC1[jj] += __builtin_amdgcn_cosf(r);
                aS1[jj] += __builtin_amdgcn_sinf(r);
                r = __builtin_amdgcn_fractf(fmaf(xv[j].y, iw1y, bp1y));
                aC1[jj] += __builtin_amdgcn_cosf(r);
                aS1[jj] += __builtin_amdgcn_sinf(r);
            }
        }
    }

    // ---- epilogue: per-wave reduce of 4 acc sets across 64 lanes ----------
    float* sl = sl_all[w];                 // private per-wave slice, no sync
    const int g  = lane >> 3;              // 0..7
    const int bb = lane & 7;

    float sums[4];
    #pragma unroll
    for (int a = 0; a < 4; ++a) {
        const float* arr = (a == 0) ? aC0 : (a == 1) ? aS0 : (a == 2) ? aC1 : aS1;
        #pragma unroll
        for (int j = 0; j < 8; ++j) sl[j * 64 + (lane ^ j)] = arr[j];
        float s = 0.f;
        #pragma unroll
        for (int k = 0; k < 8; ++k) s += sl[bb * 64 + ((g * 8 + k) ^ bb)];
        s += __shfl_xor(s, 8);
        s += __shfl_xor(s, 16);
        s += __shfl_xor(s, 32);
        sums[a] = s;
    }

    if (lane < 8) {
        const int b  = be * 8 + lane;
        const float tv = t[b];
        const float ct = cosf(tv), st = sinf(tv);
        S2[n0 * 64 + b] = make_float2(ct * sums[0] - st * sums[1],
                                      st * sums[0] + ct * sums[1]);
        S2[n1 * 64 + b] = make_float2(ct * sums[2] - st * sums[3],
                                      st * sums[2] + ct * sums[3]);
    }
}

// ---------------------------------------------------------------------------
// Kernel 2: split-K GEMM (unchanged).
// out^T[d][b] = sum_n Pr[d][n]*c[n][b] + Pi[d][n]*s[n][b]
// grid = (128 d-tiles of 8, 8 k-chunks of 256).  Wave: 2 d-rows, lanes = b.
// ---------------------------------------------------------------------------
__global__ __launch_bounds__(256) void k_gemm(
    const float2* __restrict__ S2, const float* __restrict__ Pr,
    const float* __restrict__ Pi, float* __restrict__ partial)
{
    const int lane = threadIdx.x & 63;
    const int wid  = __builtin_amdgcn_readfirstlane(threadIdx.x >> 6);
    const int d0   = blockIdx.x * 8 + wid * 2;
    const int k0   = blockIdx.y * 256;

    const float* pr = Pr + (size_t)d0 * 2048 + k0;
    const float* pi = Pi + (size_t)d0 * 2048 + k0;

    float a0 = 0.f, a1 = 0.f;

    for (int kk = 0; kk < 256; kk += 8) {
        float2 cs[8];
        #pragma unroll
        for (int i = 0; i < 8; ++i)
            cs[i] = S2[(size_t)(k0 + kk + i) * 64 + lane];
        #pragma unroll
        for (int i = 0; i < 8; ++i) {
            a0 += pr[kk + i]        * cs[i].x + pi[kk + i]        * cs[i].y;
            a1 += pr[2048 + kk + i] * cs[i].x + pi[2048 + kk + i] * cs[i].y;
        }
    }

    float* p = partial + ((size_t)blockIdx.y * 1024 + d0) * 64 + lane;
    p[0]  = a0;
    p[64] = a1;
}

// ---------------------------------------------------------------------------
// Kernel 3: reduce 8 split-K partials + SiLU (unchanged).
// ---------------------------------------------------------------------------
__global__ __launch_bounds__(256, 4) void k_reduce_silu(
    const float* __restrict__ partial, float* __restrict__ out)
{
    const int lane = threadIdx.x & 63;
    const int gw   = blockIdx.x * 4 + (threadIdx.x >> 6);
    const int b    = gw >> 4;
    const int d    = ((gw & 15) << 6) + lane;

    float s = 0.f;
    #pragma unroll
    for (int ss = 0; ss < 8; ++ss)
        s += partial[((size_t)ss * 1024 + d) * 64 + b];

    float sig = 1.0f / (1.0f + __expf(-s));
    out[(size_t)b * 1024 + d] = s * sig;
}

// ---------------------------------------------------------------------------
extern "C" void kernel_launch(void* const* d_in, const int* in_sizes, int n_in,
                              void* d_out, int out_size, void* d_ws, size_t ws_size,
                              hipStream_t stream)
{
    const float* x  = (const float*)d_in[0];   // (64,1024)
    const float* t  = (const float*)d_in[1];   // (64,)
    const float* W  = (const float*)d_in[2];   // (2048,1024)
    const float* Bp = (const float*)d_in[3];   // (2048,1024)
    const float* Pr = (const float*)d_in[4];   // (1024,2048)
    const float* Pi = (const float*)d_in[5];   // (1024,2048)
    // d_in[6], d_in[7]: sin/cos LUT — superseded by hw sin/cos

    float*  out     = (float*)d_out;                       // (64,1024) f32
    float2* S2      = (float2*)d_ws;                       // 1 MB
    float*  partial = (float*)((char*)d_ws + (1 << 20));   // 2 MB

    k_sums<<<2048, 256, 0, stream>>>(x, t, W, Bp, S2);
    k_gemm<<<dim3(128, 8), 256, 0, stream>>>(S2, Pr, Pi, partial);
    k_reduce_silu<<<256, 256, 0, stream>>>(partial, out);
}